// Round 8
// baseline (314.084 us; speedup 1.0000x reference)
//
#include <hip/hip_runtime.h>

typedef __attribute__((ext_vector_type(8))) short short8;
typedef __attribute__((ext_vector_type(4))) float f32x4;

#define IN_F 256
#define OUT_F 128
#define NPB 256          // nodes per bucket (bucket = node >> 8)
#define MAXCAP 5120      // slots per bucket (mean 4092, +16 sigma)

__device__ __forceinline__ float bf2f(unsigned int u16) {
    union { unsigned int i; float f; } v; v.i = u16 << 16; return v.f;
}
__device__ __forceinline__ unsigned short f2bf(float f) {
    union { float f; unsigned int i; } v; v.f = f;
    unsigned int u = v.i;
    return (unsigned short)((u + 0x7fffu + ((u >> 16) & 1u)) >> 16);
}

// ---------------- pass 1: bucket-bin edges, packed (src<<8)|c_local ----------------
__global__ __launch_bounds__(256) void k_bin(const int* __restrict__ row, const int* __restrict__ col,
                                             int* __restrict__ bcur, int* __restrict__ ebuf,
                                             int E, int NBr, int chunk) {
    __shared__ int hist[512];
    __shared__ int cbase[512];
    int t = threadIdx.x;
    int e0 = blockIdx.x * chunk;
    int e1 = e0 + chunk; if (e1 > E) e1 = E;

    for (int i = t; i < NBr; i += 256) hist[i] = 0;
    __syncthreads();
    for (int i = e0 + t; i < e1; i += 256)
        atomicAdd(&hist[col[i] >> 8], 1);
    __syncthreads();
    for (int i = t; i < NBr; i += 256) {
        int h = hist[i];
        cbase[i] = h ? atomicAdd(&bcur[i], h) : 0;
    }
    __syncthreads();
    for (int i = t; i < NBr; i += 256) hist[i] = 0;
    __syncthreads();
    for (int i = e0 + t; i < e1; i += 256) {
        int c = col[i];
        int r = row[i];
        int b = c >> 8;
        int p = atomicAdd(&hist[b], 1) + cbase[b];
        ebuf[(size_t)b * MAXCAP + p] = (r << 8) | (c & 255);
    }
}

// ---------------- pass 2: per-bucket fine sort + deg/offs/dis, LDS atomics only ----------------
__global__ __launch_bounds__(256) void k_fine(const int* __restrict__ bcur, const int* __restrict__ ebuf,
                                              int* __restrict__ offs, int* __restrict__ deg,
                                              float* __restrict__ dis, int* __restrict__ srci, int N) {
    __shared__ int dl[256];
    __shared__ int sc[256];
    int b = blockIdx.x;
    int t = threadIdx.x;
    int count = bcur[b];
    const int* eb = ebuf + (size_t)b * MAXCAP;

    dl[t] = 0;
    __syncthreads();
    for (int i = t; i < count; i += 256)
        atomicAdd(&dl[eb[i] & 255], 1);
    __syncthreads();
    int myDeg = dl[t];
    sc[t] = myDeg; __syncthreads();
    for (int off = 1; off < 256; off <<= 1) {
        int a = (t >= off) ? sc[t - off] : 0;
        __syncthreads();
        sc[t] += a;
        __syncthreads();
    }
    int excl = sc[t] - myDeg;
    int node = (b << 8) + t;
    int bbase = b * MAXCAP;
    if (node < N) {
        offs[node] = bbase + excl;
        deg[node] = myDeg;
        dis[node] = rsqrtf((float)myDeg + 1.0f);
    }
    dl[t] = excl;
    __syncthreads();
    for (int i = t; i < count; i += 256) {
        int p = eb[i];
        int pos = atomicAdd(&dl[p & 255], 1);
        srci[bbase + pos] = p >> 8;
    }
}

// ---------------- transpose+convert W f32 -> Wt[128][256] bf16 ; zero hb row N ----------------
__global__ __launch_bounds__(256) void k_transposeW(const float* __restrict__ W,
                                                    unsigned short* __restrict__ Wt,
                                                    unsigned short* __restrict__ hb, int N) {
    int idx = blockIdx.x * 256 + threadIdx.x;
    if (idx < IN_F * OUT_F) {
        int k = idx >> 7;
        int n = idx & 127;
        Wt[n * IN_F + k] = f2bf(W[idx]);
    }
    if (idx < OUT_F) hb[(size_t)N * OUT_F + idx] = 0;
}

// ---------------- GEMM: hb[r][:] = bf16( (bf16(x[r]) @ W + b) * dis[r] ) ----------------
// x staged via global_load_lds DMA into wave-private LDS (XOR-swizzled), double-buffered,
// no barriers; fine-grained vmcnt keeps next-step DMA in flight during compute.
__global__ __launch_bounds__(256) void k_gemm(const float* __restrict__ x,
                                              const unsigned short* __restrict__ Wt,
                                              const float* __restrict__ bias,
                                              const float* __restrict__ dis,
                                              unsigned short* __restrict__ hb, int nrows) {
    __shared__ float4 xs[2][1024];   // [buf][slot]; wave w owns slots [w*256, w*256+256)

    int t = threadIdx.x;
    int wave = t >> 6;
    int lane = t & 63;
    int m = lane & 15;
    int quad = lane >> 4;
    int row0 = blockIdx.x * 128;
    int nm1 = nrows - 1;

    // staging lane constants: slot s -> LDS row r = s>>3, fetch global float4 cg = (s&7)^(r&7)
    const short8* wf = (const short8*)Wt + (size_t)m * 32 + quad;   // frag(ct,i) = wf[ct*512 + i*4]

#define STAGE(ks, buf)                                                                     \
    do {                                                                                   \
        _Pragma("unroll")                                                                  \
        for (int j = 0; j < 4; j++) {                                                      \
            int s = wave * 256 + j * 64 + lane;                                            \
            int r = s >> 3;                                                                \
            int cg = (s & 7) ^ (r & 7);                                                    \
            int gr = row0 + r; if (gr > nm1) gr = nm1;                                     \
            const float* ga = x + (size_t)gr * IN_F + (ks) * 32 + cg * 4;                  \
            __builtin_amdgcn_global_load_lds(                                              \
                (const __attribute__((address_space(1))) unsigned int*)(const void*)ga,    \
                (__attribute__((address_space(3))) unsigned int*)(void*)&xs[buf][wave * 256 + j * 64], \
                16, 0, 0);                                                                 \
        }                                                                                  \
    } while (0)

    f32x4 acc[2][8];
#pragma unroll
    for (int tt = 0; tt < 2; tt++)
#pragma unroll
        for (int ct = 0; ct < 8; ct++) acc[tt][ct] = (f32x4){0.f, 0.f, 0.f, 0.f};

    int rA = wave * 32 + m;       // LDS row, tile 0; tile 1 = rA+16 (same &7)
    int eA = rA & 7;
    int uA = rA * 8;
    int uB = (rA + 16) * 8;
    int c0 = (2 * quad) ^ eA;
    int c1 = (2 * quad + 1) ^ eA;

    STAGE(0, 0);   // prologue

#pragma unroll
    for (int i = 0; i < 8; i++) {
        // 1) Wt fragment loads (L1/L2-hot), issued before the next-step DMA
        short8 w[8];
#pragma unroll
        for (int ct = 0; ct < 8; ct++) w[ct] = wf[ct * 512 + i * 4];

        // 2) stage next k-step into the other buffer
        if (i < 7) STAGE(i + 1, (i + 1) & 1);

        // 3) wait: drain everything older than [Wt(8) + nextDMA(4)] -> this step's buffer ready
        if (i < 7) __builtin_amdgcn_s_waitcnt(0x0F7C);   // vmcnt(12)
        else       __builtin_amdgcn_s_waitcnt(0x0F78);   // vmcnt(8)

        // 4) read this wave's x fragments from LDS (swizzled), convert to bf16
        int buf = i & 1;
        float4 xa0 = xs[buf][uA + c0];
        float4 xa1 = xs[buf][uA + c1];
        float4 xb0 = xs[buf][uB + c0];
        float4 xb1 = xs[buf][uB + c1];

        short8 af, bf;
        af[0] = (short)f2bf(xa0.x); af[1] = (short)f2bf(xa0.y);
        af[2] = (short)f2bf(xa0.z); af[3] = (short)f2bf(xa0.w);
        af[4] = (short)f2bf(xa1.x); af[5] = (short)f2bf(xa1.y);
        af[6] = (short)f2bf(xa1.z); af[7] = (short)f2bf(xa1.w);
        bf[0] = (short)f2bf(xb0.x); bf[1] = (short)f2bf(xb0.y);
        bf[2] = (short)f2bf(xb0.z); bf[3] = (short)f2bf(xb0.w);
        bf[4] = (short)f2bf(xb1.x); bf[5] = (short)f2bf(xb1.y);
        bf[6] = (short)f2bf(xb1.z); bf[7] = (short)f2bf(xb1.w);

#pragma unroll
        for (int ct = 0; ct < 8; ct++)
            acc[0][ct] = __builtin_amdgcn_mfma_f32_16x16x32_bf16(af, w[ct], acc[0][ct], 0, 0, 0);
#pragma unroll
        for (int ct = 0; ct < 8; ct++)
            acc[1][ct] = __builtin_amdgcn_mfma_f32_16x16x32_bf16(bf, w[ct], acc[1][ct], 0, 0, 0);
    }
#undef STAGE

    float bv[8];
#pragma unroll
    for (int ct = 0; ct < 8; ct++) bv[ct] = bias[ct * 16 + m];

    int orow0 = blockIdx.x * 128 + wave * 32 + quad * 4;
#pragma unroll
    for (int tt = 0; tt < 2; tt++) {
#pragma unroll
        for (int r = 0; r < 4; r++) {
            int orow = orow0 + tt * 16 + r;
            if (orow < nrows) {
                float dr = dis[orow];
#pragma unroll
                for (int ct = 0; ct < 8; ct++)
                    hb[(size_t)orow * OUT_F + ct * 16 + m] = f2bf((acc[tt][ct][r] + bv[ct]) * dr);
            }
        }
    }
}

// ---------------- aggregation: wave/node, coop src load + unroll-8 gathers, add-only ----------------
__global__ __launch_bounds__(256) void k_agg(const unsigned short* __restrict__ hb,
                                             const float* __restrict__ dis,
                                             const int* __restrict__ offs, const int* __restrict__ deg,
                                             const int* __restrict__ srci,
                                             float* __restrict__ out, int n) {
    int node = blockIdx.x * 4 + (threadIdx.x >> 6);
    if (node >= n) return;
    int lane = threadIdx.x & 63;

    unsigned int v = *(const unsigned int*)(hb + (size_t)node * OUT_F + lane * 2);
    float ax = bf2f(v & 0xffffu);
    float ay = bf2f(v >> 16);

    int start = offs[node];
    int cnt = deg[node];

    for (int base = 0; base < cnt; base += 64) {
        int mm = cnt - base; if (mm > 64) mm = 64;
        int e = (lane < mm) ? srci[start + base + lane] : n;
        int mround = (mm + 7) & ~7;
        for (int j = 0; j < mround; j += 8) {
            int rr[8];
#pragma unroll
            for (int k = 0; k < 8; k++) rr[k] = __shfl(e, j + k);
            unsigned int w[8];
#pragma unroll
            for (int k = 0; k < 8; k++)
                w[k] = *(const unsigned int*)(hb + (size_t)rr[k] * OUT_F + lane * 2);
#pragma unroll
            for (int k = 0; k < 8; k++) {
                ax += bf2f(w[k] & 0xffffu);
                ay += bf2f(w[k] >> 16);
            }
        }
    }

    float di = dis[node];
    float2 o;
    o.x = fmaxf(ax * di, 0.f);
    o.y = fmaxf(ay * di, 0.f);
    *(float2*)(out + (size_t)node * OUT_F + lane * 2) = o;
}

static inline size_t alignup(size_t v, size_t a) { return (v + a - 1) & ~(a - 1); }

extern "C" void kernel_launch(void* const* d_in, const int* in_sizes, int n_in,
                              void* d_out, int out_size, void* d_ws, size_t ws_size,
                              hipStream_t stream) {
    const float* x  = (const float*)d_in[0];
    const int* ei   = (const int*)d_in[1];
    const float* W  = (const float*)d_in[2];
    const float* b  = (const float*)d_in[3];
    float* out      = (float*)d_out;

    const int N = in_sizes[0] / IN_F;      // 100000
    const int E = in_sizes[1] / 2;         // 1600000
    const int* rowp = ei;
    const int* colp = ei + E;

    const int NBr = (N + NPB - 1) / NPB;   // 391 buckets (<= 512)

    // workspace carve (~44 MB total)
    char* ws = (char*)d_ws;
    size_t off = 0;
    int*   bcur   = (int*)(ws + off);   off = alignup(off + (size_t)NBr * 4, 256);
    int*   deg    = (int*)(ws + off);   off = alignup(off + (size_t)N * 4, 256);
    float* dis    = (float*)(ws + off); off = alignup(off + (size_t)N * 4, 256);
    int*   offs   = (int*)(ws + off);   off = alignup(off + (size_t)N * 4, 256);
    unsigned short* Wt = (unsigned short*)(ws + off); off = alignup(off + (size_t)IN_F * OUT_F * 2, 256);
    int*   ebuf   = (int*)(ws + off);   off = alignup(off + (size_t)NBr * MAXCAP * 4, 256);
    int*   srci   = (int*)(ws + off);   off = alignup(off + (size_t)NBr * MAXCAP * 4, 256);
    unsigned short* hb = (unsigned short*)(ws + off); off = alignup(off + (size_t)(N + 1) * OUT_F * 2, 256);

    (void)hipMemsetAsync(bcur, 0, (size_t)NBr * 4, stream);

    int chunk = (E + 511) / 512;           // 3125 edges/block
    k_bin<<<512, 256, 0, stream>>>(rowp, colp, bcur, ebuf, E, NBr, chunk);
    k_fine<<<NBr, 256, 0, stream>>>(bcur, ebuf, offs, deg, dis, srci, N);

    k_transposeW<<<(IN_F * OUT_F + 255) / 256, 256, 0, stream>>>(W, Wt, hb, N);
    k_gemm<<<(N + 127) / 128, 256, 0, stream>>>(x, Wt, b, dis, hb, N);

    k_agg<<<(N + 3) / 4, 256, 0, stream>>>(hb, dis, offs, deg, srci, out, N);
}